// Round 9
// baseline (1137.955 us; speedup 1.0000x reference)
//
#include <hip/hip_runtime.h>
#include <hip/hip_bf16.h>
#include <stdint.h>

typedef __hip_bfloat16 bf16;
typedef unsigned long long u64;
typedef unsigned short u16;

static __device__ __forceinline__ float ldin(const void* p, long i, int f32) {
    return f32 ? ((const float*)p)[i] : __bfloat162float(((const bf16*)p)[i]);
}

// ---------------- probe: ctl[0]=0, ctl[1]=f32 flag ----------------
__global__ void k_probe(const void* x, unsigned* ctl) {
    int tid = threadIdx.x;
    int good = 0;
    for (int i = tid; i < 1024; i += 256) {
        float v = __bfloat162float(((const bf16*)x)[2 * i]);
        float a = fabsf(v);
        if (v == 0.0f || (isfinite(v) && a >= 1e-4f && a <= 100.0f)) good++;
    }
    __shared__ int s[256];
    s[tid] = good; __syncthreads();
    for (int st = 128; st > 0; st >>= 1) {
        if (tid < st) s[tid] += s[tid + st];
        __syncthreads();
    }
    if (tid == 0) { ctl[0] = 0u; ctl[1] = (s[0] >= 700) ? 0u : 1u; }
}

__global__ void k_sentinel(void* outv, const unsigned* ctl, float val) {
    int i = blockIdx.x * 256 + threadIdx.x;
    if (i >= 64000) return;
    if (ctl[1]) ((float*)outv)[i] = val;
    else ((bf16*)outv)[i] = __float2bfloat16(val);
}

// ---------------- mega prep ----------------
__device__ __forceinline__ void pack_convw_task(const void* w, uint2* wp, int Co, int f32,
                                                int bx, int tid) {
    int t = bx * 256 + tid;
    if (t >= Co * 41) return;
    int co = t / 41, k = t % 41;
    unsigned w0 = 0, w1 = 0;
    for (int c = 0; c < 32; c++)
        if (ldin(w, (co * 64 + c) * 41 + k, f32) > 0.f) w0 |= (1u << c);
    for (int c = 0; c < 32; c++)
        if (ldin(w, (co * 64 + 32 + c) * 41 + k, f32) > 0.f) w1 |= (1u << c);
    wp[t] = make_uint2(w0, w1);
}
__device__ __forceinline__ void pack_rows_task(const void* w, unsigned* wp, int rows, int F,
                                               int f32, int bx, int tid) {
    int Fw = F >> 5;
    int t = bx * 256 + tid;
    if (t >= rows * Fw) return;
    int r = t / Fw, wi = t % Fw;
    unsigned m = 0;
    for (int j = 0; j < 32; j++)
        if (ldin(w, (long)r * F + wi * 32 + j, f32) > 0.f) m |= (1u << j);
    wp[t] = m;
}

__global__ void k_prep(const void* x, const void* c1w, const void* c2w, const void* c3w,
                       const void* c4w, const void* c5w, const void* f1w, const void* f2w,
                       float* ws1f, uint2* w2p, uint2* w3p, uint2* w4p, uint2* w5p,
                       unsigned* fc1wp, unsigned* fc2wp, u64* stats, double* part0,
                       const unsigned* ctl) {
    int f32 = ctl[1];
    int task = blockIdx.y, bx = blockIdx.x, tid = threadIdx.x;
    switch (task) {
        case 0: {
            int i = bx * 256 + tid;
            if (i < 7872) {
                float v = ldin(c1w, i, f32);
                ws1f[i] = (v > 0.f) ? 1.f : ((v < 0.f) ? -1.f : 0.f);
            }
        } break;
        case 1: pack_convw_task(c2w, w2p, 64, f32, bx, tid); break;
        case 2: pack_convw_task(c3w, w3p, 64, f32, bx, tid); break;
        case 3: pack_convw_task(c4w, w4p, 64, f32, bx, tid); break;
        case 4: pack_convw_task(c5w, w5p, 32, f32, bx, tid); break;
        case 5: pack_rows_task(f1w, fc1wp, 1024, 832, f32, bx, tid); break;
        case 6: pack_rows_task(f2w, fc2wp, 1000, 1024, f32, bx, tid); break;
        case 7: {
            int i = bx * 256 + tid;
            if (i < 14336) stats[i] = 0ull;   // int-stats (12288) + f64 y-buckets (2048)
        } break;
        case 8: {
            if (bx >= 96) return;
            int c = bx >> 5, s = bx & 31;
            double s1 = 0, s2 = 0;
            for (int n = 0; n < 64; n++) {
                long base = (long)(n * 3 + c) * 16000;
                for (int l = s * 256 + tid; l < 16000; l += 32 * 256) {
                    double v = (double)ldin(x, base + l, f32);
                    s1 += v; s2 += v * v;
                }
            }
            __shared__ double a1[256], a2[256];
            a1[tid] = s1; a2[tid] = s2;
            __syncthreads();
            for (int st = 128; st > 0; st >>= 1) {
                if (tid < st) { a1[tid] += a1[tid + st]; a2[tid] += a2[tid + st]; }
                __syncthreads();
            }
            if (tid == 0) { part0[(c * 32 + s) * 2] = a1[0]; part0[(c * 32 + s) * 2 + 1] = a2[0]; }
        } break;
    }
}

// ---------------- conv1: f32 FMA (full-rate v_fma_f32), borderline guard in pack_y ----------------
// grid (83, 64); pooled lp = bx*64+lane; tile [bx*192, bx*192+272)
// History: f64 dot16 = 437us (quarter-rate f64 fma); int24 mad = 465us (ALSO quarter-rate on
// gfx950 — measured round 8); f32 fma is the only full-rate MAD (103 TF, m07).
// launch_bounds(256,4): proven non-spilling budget (round 7's (256,5) spilled -> 6.9 GB scratch).
__global__ __launch_bounds__(256, 4) void k_conv1(const void* __restrict__ x,
                                                  const double* __restrict__ part0,
                                                  const void* __restrict__ g0,
                                                  const void* __restrict__ b0,
                                                  const float* __restrict__ wsf,
                                                  float* __restrict__ yq,
                                                  double* __restrict__ yb,
                                                  const unsigned* __restrict__ ctl) {
    __shared__ float xt[3][272];
    __shared__ double2 b0s[3];
    int f32 = ctl[1];
    int n = blockIdx.y, bx = blockIdx.x, tid = threadIdx.x;
    if (tid < 3) {   // fold bn0 finalize
        int c = tid;
        double s1 = 0, s2 = 0;
        for (int s = 0; s < 32; s++) { s1 += part0[(c * 32 + s) * 2]; s2 += part0[(c * 32 + s) * 2 + 1]; }
        double M = 64.0 * 16000.0;
        double mu = s1 / M, var = s2 / M - mu * mu;
        double A = (double)ldin(g0, c, f32) / sqrt(var + 1e-5);
        b0s[c] = make_double2(A, (double)ldin(b0, c, f32) - mu * A);
    }
    __syncthreads();
    int base = bx * 192;
    for (int i = tid; i < 816; i += 256) {
        int c = i / 272, j = i % 272;
        int pos = base + j;
        float q = 0.f;
        if (pos < 16000) {
            double2 p = b0s[c];
            double v = (double)ldin(x, (long)(n * 3 + c) * 16000 + pos, f32) * p.x + p.y;
            v = fmin(fmax(v, -1.0), 1.0);
            q = (float)v;   // f32 quantization: |err| <= 2^-25 per element
        }
        xt[c][i % 272] = q;
    }
    __syncthreads();

    int lane = tid & 63;
    int wave = __builtin_amdgcn_readfirstlane(tid >> 6);
    int co0 = wave * 16;

    float acc[16][3] = {};
#pragma unroll 1
    for (int c = 0; c < 3; c++) {
        const float* xr = &xt[c][3 * lane];
        const float* wr = wsf + co0 * 123 + c * 41;
        float x0 = xr[0];
#pragma unroll 1
        for (int kc = 0; kc < 40; kc += 4) {
#pragma unroll
            for (int kk = 0; kk < 4; kk++) {
                int k = kc + kk;
                float x1 = xr[2 * k + 1];
                float x2 = xr[2 * k + 2];
#pragma unroll
                for (int j = 0; j < 16; j++) {
                    float wv = wr[j * 123 + k];
                    acc[j][0] = fmaf(wv, x0, acc[j][0]);
                    acc[j][1] = fmaf(wv, x1, acc[j][1]);
                    acc[j][2] = fmaf(wv, x2, acc[j][2]);
                }
                x0 = x2;
            }
        }
        float x1 = xr[81], x2 = xr[82];
#pragma unroll
        for (int j = 0; j < 16; j++) {
            float wv = wr[j * 123 + 40];
            acc[j][0] = fmaf(wv, x0, acc[j][0]);
            acc[j][1] = fmaf(wv, x1, acc[j][1]);
            acc[j][2] = fmaf(wv, x2, acc[j][2]);
        }
    }

    int lp = bx * 64 + lane;
    bool ok = lp < 5306;
    int sb = bx & 15;
#pragma unroll
    for (int j = 0; j < 16; j++) {
        float mq = fmaxf(fmaxf(acc[j][0], acc[j][1]), acc[j][2]);   // maxpool3 (bias cancels in bn1)
        if (ok) yq[((size_t)n * 64 + co0 + j) * 5306 + lp] = mq;
        double s = ok ? (double)mq : 0.0;
        double q = s * s;
        for (int off = 32; off > 0; off >>= 1) {
            s += __shfl_down(s, off, 64);
            q += __shfl_down(q, off, 64);
        }
        if (lane == 0) {
            atomicAdd(&yb[((co0 + j) * 16 + sb) * 2], s);
            atomicAdd(&yb[((co0 + j) * 16 + sb) * 2 + 1], q);
        }
    }
}

// ---------------- pack_y: bn1 finalize + sign + borderline f64 recompute ----------------
// grid (21, 64). Window 2e-3: rigorous f32 dot error bound is 4.6e-4 (4x slack).
__global__ void k_pack_y(const float* __restrict__ yq, const double* __restrict__ yb,
                         const void* g1, const void* b1,
                         const void* __restrict__ x, const void* __restrict__ c1w,
                         const double* __restrict__ part0, const void* g0, const void* b0,
                         uint2* __restrict__ xp, const unsigned* __restrict__ ctl) {
    __shared__ double2 pqs[64];   // (A, B) per channel, y-units
    __shared__ double2 b0s[3];
    int f32 = ctl[1];
    int tid = threadIdx.x;
    if (tid < 64) {
        int c = tid;
        double s1 = 0, s2 = 0;
        for (int s = 0; s < 16; s++) { s1 += yb[(c * 16 + s) * 2]; s2 += yb[(c * 16 + s) * 2 + 1]; }
        double M = 64.0 * 5306.0;
        double mu = s1 / M;
        double var = s2 / M - mu * mu;
        double A = (double)ldin(g1, c, f32) / sqrt(var + 1e-5);
        pqs[c] = make_double2(A, (double)ldin(b1, c, f32) - mu * A);
    }
    if (tid >= 64 && tid < 67) {
        int c = tid - 64;
        double s1 = 0, s2 = 0;
        for (int s = 0; s < 32; s++) { s1 += part0[(c * 32 + s) * 2]; s2 += part0[(c * 32 + s) * 2 + 1]; }
        double M = 64.0 * 16000.0;
        double mu = s1 / M, var = s2 / M - mu * mu;
        double A = (double)ldin(g0, c, f32) / sqrt(var + 1e-5);
        b0s[c] = make_double2(A, (double)ldin(b0, c, f32) - mu * A);
    }
    __syncthreads();
    int n = blockIdx.y;
    int l = blockIdx.x * 256 + tid;
    if (l >= 5306) return;
    unsigned w0 = 0, w1 = 0;
    for (int c = 0; c < 64; c++) {
        double2 p = pqs[c];
        double yd = (double)yq[((size_t)n * 64 + c) * 5306 + l];
        double v = yd * p.x + p.y;
        if (fabs(v) < 2e-3 * fabs(p.x)) {
            // borderline: exact f64 recompute of this pooled output
            double best = -1e300;
            for (int r = 0; r < 3; r++) {
                int pp = 3 * l + r;
                double acc = 0.0;
                for (int cc = 0; cc < 3; cc++) {
                    double2 pb = b0s[cc];
                    for (int k = 0; k < 41; k++) {
                        float wf = ldin(c1w, (c * 3 + cc) * 41 + k, f32);
                        double sgn = (wf > 0.f) ? 1.0 : ((wf < 0.f) ? -1.0 : 0.0);
                        double xv = (double)ldin(x, (long)(n * 3 + cc) * 16000 + pp + 2 * k, f32);
                        xv = fmin(fmax(xv * pb.x + pb.y, -1.0), 1.0);
                        acc = fma(sgn, xv, acc);
                    }
                }
                best = fmax(best, acc);
            }
            v = best * p.x + p.y;
        }
        if (v > 0.0) { if (c < 32) w0 |= 1u << c; else w1 |= 1u << (c - 32); }
    }
    xp[(size_t)n * 5306 + l] = make_uint2(w0, w1);
}

// ---------------- binary conv from packed input (conv2) ----------------
__global__ __launch_bounds__(256) void k_conv_bin(const uint2* __restrict__ xp,
                                                  const uint2* __restrict__ wp,
                                                  u16* __restrict__ mout,
                                                  int Lp, int Lin, int Co,
                                                  u64* __restrict__ stat) {
    int n = blockIdx.y, tid = threadIdx.x;
    int lane = tid & 63;
    int wave = __builtin_amdgcn_readfirstlane(tid >> 6);
    int co0 = blockIdx.z * 32 + wave * 8;
    int base = blockIdx.x * 192;
    int lp = blockIdx.x * 64 + lane;

    __shared__ uint2 xt[272];
    for (int i = tid; i < 272; i += 256) {
        int pos = base + i;
        xt[i] = (pos < Lin) ? xp[(size_t)n * Lin + pos] : make_uint2(0u, 0u);
    }
    __syncthreads();

    int acc[8][3] = {};
    uint2 xa = xt[3 * lane];
    for (int k = 0; k < 41; k++) {
        uint2 xb = xt[3 * lane + 2 * k + 1];
        uint2 xc = xt[3 * lane + 2 * k + 2];
#pragma unroll
        for (int j = 0; j < 8; j++) {
            uint2 w = wp[(co0 + j) * 41 + k];
            acc[j][0] += __popc(w.x ^ xa.x) + __popc(w.y ^ xa.y);
            acc[j][1] += __popc(w.x ^ xb.x) + __popc(w.y ^ xb.y);
            acc[j][2] += __popc(w.x ^ xc.x) + __popc(w.y ^ xc.y);
        }
        xa = xc;
    }
    bool ok = lp < Lp;
    int sb = blockIdx.x & 15;
#pragma unroll
    for (int j = 0; j < 8; j++) {
        int m = min(min(acc[j][0], acc[j][1]), acc[j][2]);
        if (ok) mout[((size_t)n * Co + co0 + j) * Lp + lp] = (u16)m;
        unsigned s = ok ? (unsigned)m : 0u;
        unsigned q = ok ? (unsigned)(m * m) : 0u;
        for (int off = 32; off > 0; off >>= 1) {
            s += __shfl_down(s, off, 64);
            q += __shfl_down(q, off, 64);
        }
        if (lane == 0) {
            atomicAdd(&stat[((co0 + j) * 16 + sb) * 2], (u64)s);
            atomicAdd(&stat[((co0 + j) * 16 + sb) * 2 + 1], (u64)q);
        }
    }
}

// ---------------- binary conv with fused BN(m)+pack staging (conv3/4) ----------------
__global__ __launch_bounds__(256) void k_conv_binm(const u16* __restrict__ min_,
                                                   const u64* __restrict__ statIn,
                                                   const void* g, const void* b, double M,
                                                   const uint2* __restrict__ wp,
                                                   u16* __restrict__ mout,
                                                   u64* __restrict__ statOut,
                                                   int Lp, int Lin, int Co,
                                                   const unsigned* __restrict__ ctl) {
    __shared__ double2 pqs[64];
    __shared__ uint2 xt[272];
    int f32 = ctl[1];
    int n = blockIdx.y, tid = threadIdx.x;
    if (tid < 64) {
        int c = tid;
        u64 s1 = 0, s2 = 0;
        for (int s = 0; s < 16; s++) { s1 += statIn[(c * 16 + s) * 2]; s2 += statIn[(c * 16 + s) * 2 + 1]; }
        double mu = (double)s1 / M;
        double varm = (double)s2 / M - mu * mu;
        double A = (double)ldin(g, c, f32) / sqrt(4.0 * varm + 1e-5);
        pqs[c] = make_double2(-2.0 * A, 2.0 * A * mu + (double)ldin(b, c, f32));
    }
    __syncthreads();
    int base = blockIdx.x * 192;
    for (int i = tid; i < 272; i += 256) {
        int pos = base + i;
        unsigned w0 = 0, w1 = 0;
        if (pos < Lin) {
            const u16* mp = min_ + (size_t)n * 64 * Lin + pos;
#pragma unroll 4
            for (int c = 0; c < 32; c++) {
                double2 p = pqs[c];
                if ((double)mp[(size_t)c * Lin] * p.x + p.y > 0.0) w0 |= 1u << c;
            }
#pragma unroll 4
            for (int c = 0; c < 32; c++) {
                double2 p = pqs[c + 32];
                if ((double)mp[(size_t)(c + 32) * Lin] * p.x + p.y > 0.0) w1 |= 1u << c;
            }
        }
        xt[i] = make_uint2(w0, w1);
    }
    __syncthreads();

    int lane = tid & 63;
    int wave = __builtin_amdgcn_readfirstlane(tid >> 6);
    int co0 = blockIdx.z * 32 + wave * 8;
    int lp = blockIdx.x * 64 + lane;

    int acc[8][3] = {};
    uint2 xa = xt[3 * lane];
    for (int k = 0; k < 41; k++) {
        uint2 xb = xt[3 * lane + 2 * k + 1];
        uint2 xc = xt[3 * lane + 2 * k + 2];
#pragma unroll
        for (int j = 0; j < 8; j++) {
            uint2 w = wp[(co0 + j) * 41 + k];
            acc[j][0] += __popc(w.x ^ xa.x) + __popc(w.y ^ xa.y);
            acc[j][1] += __popc(w.x ^ xb.x) + __popc(w.y ^ xb.y);
            acc[j][2] += __popc(w.x ^ xc.x) + __popc(w.y ^ xc.y);
        }
        xa = xc;
    }
    bool ok = lp < Lp;
    int sb = blockIdx.x & 15;
#pragma unroll
    for (int j = 0; j < 8; j++) {
        int m = min(min(acc[j][0], acc[j][1]), acc[j][2]);
        if (ok) mout[((size_t)n * Co + co0 + j) * Lp + lp] = (u16)m;
        if (statOut) {
            unsigned s = ok ? (unsigned)m : 0u;
            unsigned q = ok ? (unsigned)(m * m) : 0u;
            for (int off = 32; off > 0; off >>= 1) {
                s += __shfl_down(s, off, 64);
                q += __shfl_down(q, off, 64);
            }
            if (lane == 0) {
                atomicAdd(&statOut[((co0 + j) * 16 + sb) * 2], (u64)s);
                atomicAdd(&statOut[((co0 + j) * 16 + sb) * 2 + 1], (u64)q);
            }
        }
    }
}

// ---------------- conv5 + fc1 fused: grid (64) = one block per sample ----------------
__global__ void k_c5fc1(const u16* __restrict__ m4, const u64* __restrict__ s4,
                        const void* g4, const void* b4,
                        const uint2* __restrict__ w5p, const void* __restrict__ b5,
                        const unsigned* __restrict__ fc1wp, u16* __restrict__ acc1,
                        u64* __restrict__ s5, const unsigned* __restrict__ ctl) {
    __shared__ double2 pqs[64];
    __shared__ uint2 xt[280];
    __shared__ int m5s[32][26];
    __shared__ unsigned xw[26];
    int f32 = ctl[1];
    int n = blockIdx.x, tid = threadIdx.x;
    const int Lin = 158;
    if (tid < 64) {
        int c = tid;
        u64 s1 = 0, s2 = 0;
        for (int s = 0; s < 16; s++) { s1 += s4[(c * 16 + s) * 2]; s2 += s4[(c * 16 + s) * 2 + 1]; }
        double M = 64.0 * 158.0;
        double mu = (double)s1 / M;
        double varm = (double)s2 / M - mu * mu;
        double A = (double)ldin(g4, c, f32) / sqrt(4.0 * varm + 1e-5);
        pqs[c] = make_double2(-2.0 * A, 2.0 * A * mu + (double)ldin(b4, c, f32));
    }
    __syncthreads();
    for (int i = tid; i < 280; i += 256) {
        unsigned w0 = 0, w1 = 0;
        if (i < Lin) {
            const u16* mp = m4 + (size_t)n * 64 * Lin + i;
#pragma unroll 4
            for (int c = 0; c < 32; c++) {
                double2 p = pqs[c];
                if ((double)mp[(size_t)c * Lin] * p.x + p.y > 0.0) w0 |= 1u << c;
            }
#pragma unroll 4
            for (int c = 0; c < 32; c++) {
                double2 p = pqs[c + 32];
                if ((double)mp[(size_t)(c + 32) * Lin] * p.x + p.y > 0.0) w1 |= 1u << c;
            }
        }
        xt[i] = make_uint2(w0, w1);
    }
    __syncthreads();

    int lane = tid & 63;
    int wave = __builtin_amdgcn_readfirstlane(tid >> 6);
    int co0 = wave * 8;
    int acc[8][3] = {};
    uint2 xa = xt[3 * lane];
    for (int k = 0; k < 41; k++) {
        uint2 xb = xt[3 * lane + 2 * k + 1];
        uint2 xc = xt[3 * lane + 2 * k + 2];
#pragma unroll
        for (int j = 0; j < 8; j++) {
            uint2 w = w5p[(co0 + j) * 41 + k];
            acc[j][0] += __popc(w.x ^ xa.x) + __popc(w.y ^ xa.y);
            acc[j][1] += __popc(w.x ^ xb.x) + __popc(w.y ^ xb.y);
            acc[j][2] += __popc(w.x ^ xc.x) + __popc(w.y ^ xc.y);
        }
        xa = xc;
    }
    if (lane < 26) {
#pragma unroll
        for (int j = 0; j < 8; j++)
            m5s[co0 + j][lane] = min(min(acc[j][0], acc[j][1]), acc[j][2]);
    }
    __syncthreads();
    if (tid < 26) {
        unsigned mask = 0;
        for (int j = 0; j < 32; j++) {
            int f = tid * 32 + j, c = f / 26, l = f % 26;
            double yv = 2624.0 - 2.0 * (double)m5s[c][l] + (double)ldin(b5, c, f32);
            if (yv > 0.0) mask |= 1u << j;
        }
        xw[tid] = mask;
    }
    __syncthreads();
#pragma unroll
    for (int i = 0; i < 4; i++) {
        int j = tid + i * 256;
        unsigned a = 0;
        for (int w = 0; w < 26; w++) a += __popc(xw[w] ^ fc1wp[j * 26 + w]);
        acc1[n * 1024 + j] = (u16)a;
        atomicAdd(&s5[j * 2], (u64)a);
        atomicAdd(&s5[j * 2 + 1], (u64)(a * a));
    }
}

// ---------------- fc2 (+bn5 fold) and lsm (+bn6 fold) ----------------
__global__ void k_fc2(const u16* __restrict__ acc1, const u64* __restrict__ s5,
                      const void* g5, const void* b5, const unsigned* __restrict__ fc2wp,
                      u16* __restrict__ acc2, u64* __restrict__ s6, const unsigned* ctl) {
    __shared__ double2 pq5s[1024];
    __shared__ unsigned xw[32];
    int f32 = ctl[1];
    int n = blockIdx.y, tid = threadIdx.x;
    for (int f = tid; f < 1024; f += 256) {
        u64 a1 = s5[f * 2], a2 = s5[f * 2 + 1];
        double mu = (double)a1 / 64.0;
        double varm = (double)a2 / 64.0 - mu * mu;
        double A = (double)ldin(g5, f, f32) / sqrt(4.0 * varm + 1e-5);
        pq5s[f] = make_double2(-2.0 * A, 2.0 * A * mu + (double)ldin(b5, f, f32));
    }
    __syncthreads();
    if (tid < 32) {
        unsigned mask = 0;
        for (int j = 0; j < 32; j++) {
            int f = tid * 32 + j;
            double2 p = pq5s[f];
            if ((double)acc1[n * 1024 + f] * p.x + p.y > 0.0) mask |= 1u << j;
        }
        xw[tid] = mask;
    }
    __syncthreads();
    int j = blockIdx.x * 256 + tid;
    if (j >= 1000) return;
    unsigned a = 0;
    for (int w = 0; w < 32; w++) a += __popc(xw[w] ^ fc2wp[j * 32 + w]);
    acc2[n * 1000 + j] = (u16)a;
    atomicAdd(&s6[j * 2], (u64)a);
    atomicAdd(&s6[j * 2 + 1], (u64)(a * a));
}

__global__ void k_lsm(const u16* __restrict__ acc2, const u64* __restrict__ s6,
                      const void* g6, const void* b6, const unsigned* ctl, void* outv) {
    int n = blockIdx.x, tid = threadIdx.x;
    int f32 = ctl[1];
    __shared__ double red[256];
    double v[4];
    double mx = -1e300;
#pragma unroll
    for (int i = 0; i < 4; i++) {
        int j = tid + i * 256;
        if (j < 1000) {
            u64 a1 = s6[j * 2], a2 = s6[j * 2 + 1];
            double mu = (double)a1 / 64.0;
            double varm = (double)a2 / 64.0 - mu * mu;
            double A = (double)ldin(g6, j, f32) / sqrt(4.0 * varm + 1e-5);
            v[i] = (double)acc2[n * 1000 + j] * (-2.0 * A) + (2.0 * A * mu + (double)ldin(b6, j, f32));
            mx = fmax(mx, v[i]);
        } else v[i] = -1e300;
    }
    red[tid] = mx; __syncthreads();
    for (int s = 128; s > 0; s >>= 1) {
        if (tid < s) red[tid] = fmax(red[tid], red[tid + s]);
        __syncthreads();
    }
    mx = red[0]; __syncthreads();
    double sum = 0.0;
#pragma unroll
    for (int i = 0; i < 4; i++) {
        int j = tid + i * 256;
        if (j < 1000) sum += exp(v[i] - mx);
    }
    red[tid] = sum; __syncthreads();
    for (int s = 128; s > 0; s >>= 1) {
        if (tid < s) red[tid] += red[tid + s];
        __syncthreads();
    }
    double ls = log(red[0]);
#pragma unroll
    for (int i = 0; i < 4; i++) {
        int j = tid + i * 256;
        if (j < 1000) {
            float r = (float)(v[i] - mx - ls);
            if (!isfinite(r)) r = -700.0f;
            if (f32) ((float*)outv)[n * 1000 + j] = r;
            else ((bf16*)outv)[n * 1000 + j] = __float2bfloat16(r);
        }
    }
}

extern "C" void kernel_launch(void* const* d_in, const int* in_sizes, int n_in,
                              void* d_out, int out_size, void* d_ws, size_t ws_size,
                              hipStream_t stream) {
    const void* x       = d_in[0];
    const void* bn0_g   = d_in[1];
    const void* bn0_b   = d_in[2];
    const void* conv1_w = d_in[3];
    const void* bn1_g   = d_in[5];
    const void* bn1_b   = d_in[6];
    const void* conv2_w = d_in[7];
    const void* bn2_g   = d_in[9];
    const void* bn2_b   = d_in[10];
    const void* conv3_w = d_in[11];
    const void* bn3_g   = d_in[13];
    const void* bn3_b   = d_in[14];
    const void* conv4_w = d_in[15];
    const void* bn4_g   = d_in[17];
    const void* bn4_b   = d_in[18];
    const void* conv5_w = d_in[19];
    const void* conv5_b = d_in[20];
    const void* fc1_w   = d_in[21];
    const void* bn5_g   = d_in[23];
    const void* bn5_b   = d_in[24];
    const void* fc2_w   = d_in[25];
    const void* bn6_g   = d_in[27];
    const void* bn6_b   = d_in[28];

    char* wsb = (char*)d_ws;
    size_t off = 0;
    auto alloc = [&](size_t bytes) -> void* {
        off = (off + 255) & ~(size_t)255;
        void* p = wsb + off;
        off += bytes;
        return p;
    };

    unsigned* ctl   = (unsigned*)alloc(256);
    unsigned* x2p   = (unsigned*)alloc(2716672);       // 5306*64 uint2
    float*    yq    = (float*)alloc(86933504);         // 64*64*5306 f32
    u16*      m2    = (u16*)alloc(14270464);
    u16*      m3    = (u16*)alloc(4538368);
    u16*      m4    = (u16*)alloc(1294336);
    u16*      acc1  = (u16*)alloc(131072);
    u16*      acc2  = (u16*)alloc(128000);
    float*    ws1f  = (float*)alloc(31488);
    uint2*    w2p   = (uint2*)alloc(20992);
    uint2*    w3p   = (uint2*)alloc(20992);
    uint2*    w4p   = (uint2*)alloc(20992);
    uint2*    w5p   = (uint2*)alloc(10496);
    unsigned* fc1wp = (unsigned*)alloc(106496);
    unsigned* fc2wp = (unsigned*)alloc(128000);
    u64*      stats = (u64*)alloc(14336 * 8);          // s2|s3|s4|s5|s6|spare|yb(f64)
    double*   part0 = (double*)alloc(2048);
    size_t need = (off + 255) & ~(size_t)255;

    u64* s2 = stats;
    u64* s3 = stats + 2048;
    u64* s4 = stats + 4096;
    u64* s5 = stats + 6144;
    u64* s6 = stats + 8192;
    double* yb = (double*)(stats + 12288);             // 2048 f64 bn1 buckets

    k_probe<<<1, 256, 0, stream>>>(x, ctl);

    if (n_in != 29) {
        k_sentinel<<<250, 256, 0, stream>>>(d_out, ctl, -(3000.0f + (float)n_in));
        return;
    }
    if (ws_size < need) {
        k_sentinel<<<250, 256, 0, stream>>>(d_out, ctl, -1500.0f);
        return;
    }

    k_prep<<<dim3(125, 9), 256, 0, stream>>>(x, conv1_w, conv2_w, conv3_w, conv4_w, conv5_w,
                                             fc1_w, fc2_w, ws1f, w2p, w3p, w4p, w5p,
                                             fc1wp, fc2wp, stats, part0, ctl);

    k_conv1<<<dim3(83, 64), 256, 0, stream>>>(x, part0, bn0_g, bn0_b, ws1f, yq, yb, ctl);
    k_pack_y<<<dim3(21, 64), 256, 0, stream>>>(yq, yb, bn1_g, bn1_b, x, conv1_w,
                                               part0, bn0_g, bn0_b, (uint2*)x2p, ctl);

    k_conv_bin<<<dim3(28, 64, 2), 256, 0, stream>>>((const uint2*)x2p, w2p, m2, 1742, 5306, 64, s2);
    k_conv_binm<<<dim3(9, 64, 2), 256, 0, stream>>>(m2, s2, bn2_g, bn2_b, 64.0 * 1742.0,
                                                    w3p, m3, s3, 554, 1742, 64, ctl);
    k_conv_binm<<<dim3(3, 64, 2), 256, 0, stream>>>(m3, s3, bn3_g, bn3_b, 64.0 * 554.0,
                                                    w4p, m4, s4, 158, 554, 64, ctl);

    k_c5fc1<<<64, 256, 0, stream>>>(m4, s4, bn4_g, bn4_b, w5p, conv5_b, fc1wp, acc1, s5, ctl);
    k_fc2<<<dim3(4, 64), 256, 0, stream>>>(acc1, s5, bn5_g, bn5_b, fc2wp, acc2, s6, ctl);
    k_lsm<<<64, 256, 0, stream>>>(acc2, s6, bn6_g, bn6_b, ctl, d_out);
}

// Round 10
// 874.446 us; speedup vs baseline: 1.3013x; 1.3013x over previous
//
#include <hip/hip_runtime.h>
#include <hip/hip_bf16.h>
#include <stdint.h>

typedef __hip_bfloat16 bf16;
typedef unsigned long long u64;
typedef unsigned short u16;

#define FIXCAP (1u << 20)

static __device__ __forceinline__ float ldin(const void* p, long i, int f32) {
    return f32 ? ((const float*)p)[i] : __bfloat162float(((const bf16*)p)[i]);
}

// ---------------- probe: ctl[0]=0, ctl[1]=f32 flag ----------------
__global__ void k_probe(const void* x, unsigned* ctl) {
    int tid = threadIdx.x;
    int good = 0;
    for (int i = tid; i < 1024; i += 256) {
        float v = __bfloat162float(((const bf16*)x)[2 * i]);
        float a = fabsf(v);
        if (v == 0.0f || (isfinite(v) && a >= 1e-4f && a <= 100.0f)) good++;
    }
    __shared__ int s[256];
    s[tid] = good; __syncthreads();
    for (int st = 128; st > 0; st >>= 1) {
        if (tid < st) s[tid] += s[tid + st];
        __syncthreads();
    }
    if (tid == 0) { ctl[0] = 0u; ctl[1] = (s[0] >= 700) ? 0u : 1u; }
}

__global__ void k_sentinel(void* outv, const unsigned* ctl, float val) {
    int i = blockIdx.x * 256 + threadIdx.x;
    if (i >= 64000) return;
    if (ctl[1]) ((float*)outv)[i] = val;
    else ((bf16*)outv)[i] = __float2bfloat16(val);
}

// ---------------- mega prep ----------------
__device__ __forceinline__ void pack_convw_task(const void* w, uint2* wp, int Co, int f32,
                                                int bx, int tid) {
    int t = bx * 256 + tid;
    if (t >= Co * 41) return;
    int co = t / 41, k = t % 41;
    unsigned w0 = 0, w1 = 0;
    for (int c = 0; c < 32; c++)
        if (ldin(w, (co * 64 + c) * 41 + k, f32) > 0.f) w0 |= (1u << c);
    for (int c = 0; c < 32; c++)
        if (ldin(w, (co * 64 + 32 + c) * 41 + k, f32) > 0.f) w1 |= (1u << c);
    wp[t] = make_uint2(w0, w1);
}
__device__ __forceinline__ void pack_rows_task(const void* w, unsigned* wp, int rows, int F,
                                               int f32, int bx, int tid) {
    int Fw = F >> 5;
    int t = bx * 256 + tid;
    if (t >= rows * Fw) return;
    int r = t / Fw, wi = t % Fw;
    unsigned m = 0;
    for (int j = 0; j < 32; j++)
        if (ldin(w, (long)r * F + wi * 32 + j, f32) > 0.f) m |= (1u << j);
    wp[t] = m;
}

__global__ void k_prep(const void* x, const void* c1w, const void* c2w, const void* c3w,
                       const void* c4w, const void* c5w, const void* f1w, const void* f2w,
                       float* ws1f, uint2* w2p, uint2* w3p, uint2* w4p, uint2* w5p,
                       unsigned* fc1wp, unsigned* fc2wp, u64* stats, double* part0,
                       const unsigned* ctl) {
    int f32 = ctl[1];
    int task = blockIdx.y, bx = blockIdx.x, tid = threadIdx.x;
    switch (task) {
        case 0: {
            int i = bx * 256 + tid;
            if (i < 7872) {
                float v = ldin(c1w, i, f32);
                ws1f[i] = (v > 0.f) ? 1.f : ((v < 0.f) ? -1.f : 0.f);
            }
        } break;
        case 1: pack_convw_task(c2w, w2p, 64, f32, bx, tid); break;
        case 2: pack_convw_task(c3w, w3p, 64, f32, bx, tid); break;
        case 3: pack_convw_task(c4w, w4p, 64, f32, bx, tid); break;
        case 4: pack_convw_task(c5w, w5p, 32, f32, bx, tid); break;
        case 5: pack_rows_task(f1w, fc1wp, 1024, 832, f32, bx, tid); break;
        case 6: pack_rows_task(f2w, fc2wp, 1000, 1024, f32, bx, tid); break;
        case 7: {
            int i = bx * 256 + tid;
            if (i < 14400) stats[i] = 0ull;   // int-stats + yb(f64) + fixcnt
        } break;
        case 8: {
            if (bx >= 96) return;
            int c = bx >> 5, s = bx & 31;
            double s1 = 0, s2 = 0;
            for (int n = 0; n < 64; n++) {
                long base = (long)(n * 3 + c) * 16000;
                for (int l = s * 256 + tid; l < 16000; l += 32 * 256) {
                    double v = (double)ldin(x, base + l, f32);
                    s1 += v; s2 += v * v;
                }
            }
            __shared__ double a1[256], a2[256];
            a1[tid] = s1; a2[tid] = s2;
            __syncthreads();
            for (int st = 128; st > 0; st >>= 1) {
                if (tid < st) { a1[tid] += a1[tid + st]; a2[tid] += a2[tid + st]; }
                __syncthreads();
            }
            if (tid == 0) { part0[(c * 32 + s) * 2] = a1[0]; part0[(c * 32 + s) * 2 + 1] = a2[0]; }
        } break;
    }
}

// ---------------- conv1: f32 FMA (full-rate) ----------------
// grid (83, 64); pooled lp = bx*64+lane; tile [bx*192, bx*192+272)
// f64 fma & int24 mad are both quarter-rate on gfx950 (rounds 6/8); f32 fma is full-rate.
__global__ __launch_bounds__(256, 4) void k_conv1(const void* __restrict__ x,
                                                  const double* __restrict__ part0,
                                                  const void* __restrict__ g0,
                                                  const void* __restrict__ b0,
                                                  const float* __restrict__ wsf,
                                                  float* __restrict__ yq,
                                                  double* __restrict__ yb,
                                                  const unsigned* __restrict__ ctl) {
    __shared__ float xt[3][272];
    __shared__ double2 b0s[3];
    int f32 = ctl[1];
    int n = blockIdx.y, bx = blockIdx.x, tid = threadIdx.x;
    if (tid < 3) {   // fold bn0 finalize
        int c = tid;
        double s1 = 0, s2 = 0;
        for (int s = 0; s < 32; s++) { s1 += part0[(c * 32 + s) * 2]; s2 += part0[(c * 32 + s) * 2 + 1]; }
        double M = 64.0 * 16000.0;
        double mu = s1 / M, var = s2 / M - mu * mu;
        double A = (double)ldin(g0, c, f32) / sqrt(var + 1e-5);
        b0s[c] = make_double2(A, (double)ldin(b0, c, f32) - mu * A);
    }
    __syncthreads();
    int base = bx * 192;
    for (int i = tid; i < 816; i += 256) {
        int c = i / 272, j = i % 272;
        int pos = base + j;
        float q = 0.f;
        if (pos < 16000) {
            double2 p = b0s[c];
            double v = (double)ldin(x, (long)(n * 3 + c) * 16000 + pos, f32) * p.x + p.y;
            v = fmin(fmax(v, -1.0), 1.0);
            q = (float)v;
        }
        xt[c][i % 272] = q;
    }
    __syncthreads();

    int lane = tid & 63;
    int wave = __builtin_amdgcn_readfirstlane(tid >> 6);
    int co0 = wave * 16;

    float acc[16][3] = {};
#pragma unroll 1
    for (int c = 0; c < 3; c++) {
        const float* xr = &xt[c][3 * lane];
        const float* wr = wsf + co0 * 123 + c * 41;
        float x0 = xr[0];
#pragma unroll 1
        for (int kc = 0; kc < 40; kc += 4) {
#pragma unroll
            for (int kk = 0; kk < 4; kk++) {
                int k = kc + kk;
                float x1 = xr[2 * k + 1];
                float x2 = xr[2 * k + 2];
#pragma unroll
                for (int j = 0; j < 16; j++) {
                    float wv = wr[j * 123 + k];
                    acc[j][0] = fmaf(wv, x0, acc[j][0]);
                    acc[j][1] = fmaf(wv, x1, acc[j][1]);
                    acc[j][2] = fmaf(wv, x2, acc[j][2]);
                }
                x0 = x2;
            }
        }
        float x1 = xr[81], x2 = xr[82];
#pragma unroll
        for (int j = 0; j < 16; j++) {
            float wv = wr[j * 123 + 40];
            acc[j][0] = fmaf(wv, x0, acc[j][0]);
            acc[j][1] = fmaf(wv, x1, acc[j][1]);
            acc[j][2] = fmaf(wv, x2, acc[j][2]);
        }
    }

    int lp = bx * 64 + lane;
    bool ok = lp < 5306;
    int sb = bx & 15;
#pragma unroll
    for (int j = 0; j < 16; j++) {
        float mq = fmaxf(fmaxf(acc[j][0], acc[j][1]), acc[j][2]);   // maxpool3 (bias cancels in bn1)
        if (ok) yq[((size_t)n * 64 + co0 + j) * 5306 + lp] = mq;
        double s = ok ? (double)mq : 0.0;
        double q = s * s;
        for (int off = 32; off > 0; off >>= 1) {
            s += __shfl_down(s, off, 64);
            q += __shfl_down(q, off, 64);
        }
        if (lane == 0) {
            atomicAdd(&yb[((co0 + j) * 16 + sb) * 2], s);
            atomicAdd(&yb[((co0 + j) * 16 + sb) * 2 + 1], q);
        }
    }
}

// ---------------- pack_y: streaming sign + borderline list (no inline recompute) ----------------
// grid (21, 64). Window 2e-3 >= 4x the rigorous 4.6e-4 f32 dot error bound.
__global__ void k_pack_y(const float* __restrict__ yq, const double* __restrict__ yb,
                         const void* g1, const void* b1,
                         uint2* __restrict__ xp,
                         unsigned* __restrict__ fixcnt, unsigned* __restrict__ fixlist,
                         const unsigned* __restrict__ ctl) {
    __shared__ double2 pqs[64];   // (A, B) per channel
    int f32 = ctl[1];
    int tid = threadIdx.x;
    if (tid < 64) {
        int c = tid;
        double s1 = 0, s2 = 0;
        for (int s = 0; s < 16; s++) { s1 += yb[(c * 16 + s) * 2]; s2 += yb[(c * 16 + s) * 2 + 1]; }
        double M = 64.0 * 5306.0;
        double mu = s1 / M;
        double var = s2 / M - mu * mu;
        double A = (double)ldin(g1, c, f32) / sqrt(var + 1e-5);
        pqs[c] = make_double2(A, (double)ldin(b1, c, f32) - mu * A);
    }
    __syncthreads();
    int n = blockIdx.y;
    int l = blockIdx.x * 256 + tid;
    if (l >= 5306) return;
    unsigned w0 = 0, w1 = 0;
    for (int c = 0; c < 64; c++) {
        double2 p = pqs[c];
        double v = (double)yq[((size_t)n * 64 + c) * 5306 + l] * p.x + p.y;
        if (fabs(v) < 2e-3 * fabs(p.x)) {
            unsigned idx = atomicAdd(fixcnt, 1u);
            if (idx < FIXCAP) fixlist[idx] = ((unsigned)n << 19) | ((unsigned)c << 13) | (unsigned)l;
        }
        if (v > 0.0) { if (c < 32) w0 |= 1u << c; else w1 |= 1u << (c - 32); }
    }
    xp[(size_t)n * 5306 + l] = make_uint2(w0, w1);
}

// ---------------- k_fix: exact f64 recompute of listed borderline outputs ----------------
// grid 64 x 256 threads, grid-stride over the list
__global__ void k_fix(const unsigned* __restrict__ fixcnt, const unsigned* __restrict__ fixlist,
                      const double* __restrict__ yb, const void* g1, const void* b1,
                      const void* __restrict__ x, const void* __restrict__ c1w,
                      const double* __restrict__ part0, const void* g0, const void* b0,
                      unsigned* __restrict__ x2p, const unsigned* __restrict__ ctl) {
    int f32 = ctl[1];
    unsigned cnt = min(*fixcnt, FIXCAP);
    for (unsigned t = blockIdx.x * 256 + threadIdx.x; t < cnt; t += gridDim.x * 256) {
        unsigned e = fixlist[t];
        int n = e >> 19, c = (e >> 13) & 63, l = e & 8191;
        // bn1 params for channel c (exact f64, same formula as pack_y)
        double s1 = 0, s2 = 0;
        for (int s = 0; s < 16; s++) { s1 += yb[(c * 16 + s) * 2]; s2 += yb[(c * 16 + s) * 2 + 1]; }
        double M = 64.0 * 5306.0;
        double mu = s1 / M, var = s2 / M - mu * mu;
        double A = (double)ldin(g1, c, f32) / sqrt(var + 1e-5);
        double B = (double)ldin(b1, c, f32) - mu * A;
        // exact pooled conv1 output (f64, canonical order)
        double best = -1e300;
        for (int r = 0; r < 3; r++) {
            int pp = 3 * l + r;
            double acc = 0.0;
            for (int cc = 0; cc < 3; cc++) {
                double p1 = 0, p2 = 0;
                for (int s = 0; s < 32; s++) { p1 += part0[(cc * 32 + s) * 2]; p2 += part0[(cc * 32 + s) * 2 + 1]; }
                double M0 = 64.0 * 16000.0;
                double mu0 = p1 / M0, var0 = p2 / M0 - mu0 * mu0;
                double A0 = (double)ldin(g0, cc, f32) / sqrt(var0 + 1e-5);
                double B0 = (double)ldin(b0, cc, f32) - mu0 * A0;
                for (int k = 0; k < 41; k++) {
                    float wf = ldin(c1w, (c * 3 + cc) * 41 + k, f32);
                    double sgn = (wf > 0.f) ? 1.0 : ((wf < 0.f) ? -1.0 : 0.0);
                    double xv = (double)ldin(x, (long)(n * 3 + cc) * 16000 + pp + 2 * k, f32);
                    xv = fmin(fmax(xv * A0 + B0, -1.0), 1.0);
                    acc = fma(sgn, xv, acc);
                }
            }
            best = fmax(best, acc);
        }
        double v = best * A + B;
        unsigned* word = &x2p[((size_t)n * 5306 + l) * 2 + (c >> 5)];
        unsigned bit = 1u << (c & 31);
        if (v > 0.0) atomicOr(word, bit);
        else atomicAnd(word, ~bit);
    }
}

// ---------------- binary conv from packed input (conv2) ----------------
__global__ __launch_bounds__(256) void k_conv_bin(const uint2* __restrict__ xp,
                                                  const uint2* __restrict__ wp,
                                                  u16* __restrict__ mout,
                                                  int Lp, int Lin, int Co,
                                                  u64* __restrict__ stat) {
    int n = blockIdx.y, tid = threadIdx.x;
    int lane = tid & 63;
    int wave = __builtin_amdgcn_readfirstlane(tid >> 6);
    int co0 = blockIdx.z * 32 + wave * 8;
    int base = blockIdx.x * 192;
    int lp = blockIdx.x * 64 + lane;

    __shared__ uint2 xt[272];
    for (int i = tid; i < 272; i += 256) {
        int pos = base + i;
        xt[i] = (pos < Lin) ? xp[(size_t)n * Lin + pos] : make_uint2(0u, 0u);
    }
    __syncthreads();

    int acc[8][3] = {};
    uint2 xa = xt[3 * lane];
    for (int k = 0; k < 41; k++) {
        uint2 xb = xt[3 * lane + 2 * k + 1];
        uint2 xc = xt[3 * lane + 2 * k + 2];
#pragma unroll
        for (int j = 0; j < 8; j++) {
            uint2 w = wp[(co0 + j) * 41 + k];
            acc[j][0] += __popc(w.x ^ xa.x) + __popc(w.y ^ xa.y);
            acc[j][1] += __popc(w.x ^ xb.x) + __popc(w.y ^ xb.y);
            acc[j][2] += __popc(w.x ^ xc.x) + __popc(w.y ^ xc.y);
        }
        xa = xc;
    }
    bool ok = lp < Lp;
    int sb = blockIdx.x & 15;
#pragma unroll
    for (int j = 0; j < 8; j++) {
        int m = min(min(acc[j][0], acc[j][1]), acc[j][2]);
        if (ok) mout[((size_t)n * Co + co0 + j) * Lp + lp] = (u16)m;
        unsigned s = ok ? (unsigned)m : 0u;
        unsigned q = ok ? (unsigned)(m * m) : 0u;
        for (int off = 32; off > 0; off >>= 1) {
            s += __shfl_down(s, off, 64);
            q += __shfl_down(q, off, 64);
        }
        if (lane == 0) {
            atomicAdd(&stat[((co0 + j) * 16 + sb) * 2], (u64)s);
            atomicAdd(&stat[((co0 + j) * 16 + sb) * 2 + 1], (u64)q);
        }
    }
}

// ---------------- binary conv with fused BN(m)+pack staging (conv3/4) ----------------
__global__ __launch_bounds__(256) void k_conv_binm(const u16* __restrict__ min_,
                                                   const u64* __restrict__ statIn,
                                                   const void* g, const void* b, double M,
                                                   const uint2* __restrict__ wp,
                                                   u16* __restrict__ mout,
                                                   u64* __restrict__ statOut,
                                                   int Lp, int Lin, int Co,
                                                   const unsigned* __restrict__ ctl) {
    __shared__ double2 pqs[64];
    __shared__ uint2 xt[272];
    int f32 = ctl[1];
    int n = blockIdx.y, tid = threadIdx.x;
    if (tid < 64) {
        int c = tid;
        u64 s1 = 0, s2 = 0;
        for (int s = 0; s < 16; s++) { s1 += statIn[(c * 16 + s) * 2]; s2 += statIn[(c * 16 + s) * 2 + 1]; }
        double mu = (double)s1 / M;
        double varm = (double)s2 / M - mu * mu;
        double A = (double)ldin(g, c, f32) / sqrt(4.0 * varm + 1e-5);
        pqs[c] = make_double2(-2.0 * A, 2.0 * A * mu + (double)ldin(b, c, f32));
    }
    __syncthreads();
    int base = blockIdx.x * 192;
    for (int i = tid; i < 272; i += 256) {
        int pos = base + i;
        unsigned w0 = 0, w1 = 0;
        if (pos < Lin) {
            const u16* mp = min_ + (size_t)n * 64 * Lin + pos;
#pragma unroll 4
            for (int c = 0; c < 32; c++) {
                double2 p = pqs[c];
                if ((double)mp[(size_t)c * Lin] * p.x + p.y > 0.0) w0 |= 1u << c;
            }
#pragma unroll 4
            for (int c = 0; c < 32; c++) {
                double2 p = pqs[c + 32];
                if ((double)mp[(size_t)(c + 32) * Lin] * p.x + p.y > 0.0) w1 |= 1u << c;
            }
        }
        xt[i] = make_uint2(w0, w1);
    }
    __syncthreads();

    int lane = tid & 63;
    int wave = __builtin_amdgcn_readfirstlane(tid >> 6);
    int co0 = blockIdx.z * 32 + wave * 8;
    int lp = blockIdx.x * 64 + lane;

    int acc[8][3] = {};
    uint2 xa = xt[3 * lane];
    for (int k = 0; k < 41; k++) {
        uint2 xb = xt[3 * lane + 2 * k + 1];
        uint2 xc = xt[3 * lane + 2 * k + 2];
#pragma unroll
        for (int j = 0; j < 8; j++) {
            uint2 w = wp[(co0 + j) * 41 + k];
            acc[j][0] += __popc(w.x ^ xa.x) + __popc(w.y ^ xa.y);
            acc[j][1] += __popc(w.x ^ xb.x) + __popc(w.y ^ xb.y);
            acc[j][2] += __popc(w.x ^ xc.x) + __popc(w.y ^ xc.y);
        }
        xa = xc;
    }
    bool ok = lp < Lp;
    int sb = blockIdx.x & 15;
#pragma unroll
    for (int j = 0; j < 8; j++) {
        int m = min(min(acc[j][0], acc[j][1]), acc[j][2]);
        if (ok) mout[((size_t)n * Co + co0 + j) * Lp + lp] = (u16)m;
        if (statOut) {
            unsigned s = ok ? (unsigned)m : 0u;
            unsigned q = ok ? (unsigned)(m * m) : 0u;
            for (int off = 32; off > 0; off >>= 1) {
                s += __shfl_down(s, off, 64);
                q += __shfl_down(q, off, 64);
            }
            if (lane == 0) {
                atomicAdd(&statOut[((co0 + j) * 16 + sb) * 2], (u64)s);
                atomicAdd(&statOut[((co0 + j) * 16 + sb) * 2 + 1], (u64)q);
            }
        }
    }
}

// ---------------- conv5 + fc1 fused ----------------
__global__ void k_c5fc1(const u16* __restrict__ m4, const u64* __restrict__ s4,
                        const void* g4, const void* b4,
                        const uint2* __restrict__ w5p, const void* __restrict__ b5,
                        const unsigned* __restrict__ fc1wp, u16* __restrict__ acc1,
                        u64* __restrict__ s5, const unsigned* __restrict__ ctl) {
    __shared__ double2 pqs[64];
    __shared__ uint2 xt[280];
    __shared__ int m5s[32][26];
    __shared__ unsigned xw[26];
    int f32 = ctl[1];
    int n = blockIdx.x, tid = threadIdx.x;
    const int Lin = 158;
    if (tid < 64) {
        int c = tid;
        u64 s1 = 0, s2 = 0;
        for (int s = 0; s < 16; s++) { s1 += s4[(c * 16 + s) * 2]; s2 += s4[(c * 16 + s) * 2 + 1]; }
        double M = 64.0 * 158.0;
        double mu = (double)s1 / M;
        double varm = (double)s2 / M - mu * mu;
        double A = (double)ldin(g4, c, f32) / sqrt(4.0 * varm + 1e-5);
        pqs[c] = make_double2(-2.0 * A, 2.0 * A * mu + (double)ldin(b4, c, f32));
    }
    __syncthreads();
    for (int i = tid; i < 280; i += 256) {
        unsigned w0 = 0, w1 = 0;
        if (i < Lin) {
            const u16* mp = m4 + (size_t)n * 64 * Lin + i;
#pragma unroll 4
            for (int c = 0; c < 32; c++) {
                double2 p = pqs[c];
                if ((double)mp[(size_t)c * Lin] * p.x + p.y > 0.0) w0 |= 1u << c;
            }
#pragma unroll 4
            for (int c = 0; c < 32; c++) {
                double2 p = pqs[c + 32];
                if ((double)mp[(size_t)(c + 32) * Lin] * p.x + p.y > 0.0) w1 |= 1u << c;
            }
        }
        xt[i] = make_uint2(w0, w1);
    }
    __syncthreads();

    int lane = tid & 63;
    int wave = __builtin_amdgcn_readfirstlane(tid >> 6);
    int co0 = wave * 8;
    int acc[8][3] = {};
    uint2 xa = xt[3 * lane];
    for (int k = 0; k < 41; k++) {
        uint2 xb = xt[3 * lane + 2 * k + 1];
        uint2 xc = xt[3 * lane + 2 * k + 2];
#pragma unroll
        for (int j = 0; j < 8; j++) {
            uint2 w = w5p[(co0 + j) * 41 + k];
            acc[j][0] += __popc(w.x ^ xa.x) + __popc(w.y ^ xa.y);
            acc[j][1] += __popc(w.x ^ xb.x) + __popc(w.y ^ xb.y);
            acc[j][2] += __popc(w.x ^ xc.x) + __popc(w.y ^ xc.y);
        }
        xa = xc;
    }
    if (lane < 26) {
#pragma unroll
        for (int j = 0; j < 8; j++)
            m5s[co0 + j][lane] = min(min(acc[j][0], acc[j][1]), acc[j][2]);
    }
    __syncthreads();
    if (tid < 26) {
        unsigned mask = 0;
        for (int j = 0; j < 32; j++) {
            int f = tid * 32 + j, c = f / 26, l = f % 26;
            double yv = 2624.0 - 2.0 * (double)m5s[c][l] + (double)ldin(b5, c, f32);
            if (yv > 0.0) mask |= 1u << j;
        }
        xw[tid] = mask;
    }
    __syncthreads();
#pragma unroll
    for (int i = 0; i < 4; i++) {
        int j = tid + i * 256;
        unsigned a = 0;
        for (int w = 0; w < 26; w++) a += __popc(xw[w] ^ fc1wp[j * 26 + w]);
        acc1[n * 1024 + j] = (u16)a;
        atomicAdd(&s5[j * 2], (u64)a);
        atomicAdd(&s5[j * 2 + 1], (u64)(a * a));
    }
}

// ---------------- fc2 (+bn5 fold) and lsm (+bn6 fold) ----------------
__global__ void k_fc2(const u16* __restrict__ acc1, const u64* __restrict__ s5,
                      const void* g5, const void* b5, const unsigned* __restrict__ fc2wp,
                      u16* __restrict__ acc2, u64* __restrict__ s6, const unsigned* ctl) {
    __shared__ double2 pq5s[1024];
    __shared__ unsigned xw[32];
    int f32 = ctl[1];
    int n = blockIdx.y, tid = threadIdx.x;
    for (int f = tid; f < 1024; f += 256) {
        u64 a1 = s5[f * 2], a2 = s5[f * 2 + 1];
        double mu = (double)a1 / 64.0;
        double varm = (double)a2 / 64.0 - mu * mu;
        double A = (double)ldin(g5, f, f32) / sqrt(4.0 * varm + 1e-5);
        pq5s[f] = make_double2(-2.0 * A, 2.0 * A * mu + (double)ldin(b5, f, f32));
    }
    __syncthreads();
    if (tid < 32) {
        unsigned mask = 0;
        for (int j = 0; j < 32; j++) {
            int f = tid * 32 + j;
            double2 p = pq5s[f];
            if ((double)acc1[n * 1024 + f] * p.x + p.y > 0.0) mask |= 1u << j;
        }
        xw[tid] = mask;
    }
    __syncthreads();
    int j = blockIdx.x * 256 + tid;
    if (j >= 1000) return;
    unsigned a = 0;
    for (int w = 0; w < 32; w++) a += __popc(xw[w] ^ fc2wp[j * 32 + w]);
    acc2[n * 1000 + j] = (u16)a;
    atomicAdd(&s6[j * 2], (u64)a);
    atomicAdd(&s6[j * 2 + 1], (u64)(a * a));
}

__global__ void k_lsm(const u16* __restrict__ acc2, const u64* __restrict__ s6,
                      const void* g6, const void* b6, const unsigned* ctl, void* outv) {
    int n = blockIdx.x, tid = threadIdx.x;
    int f32 = ctl[1];
    __shared__ double red[256];
    double v[4];
    double mx = -1e300;
#pragma unroll
    for (int i = 0; i < 4; i++) {
        int j = tid + i * 256;
        if (j < 1000) {
            u64 a1 = s6[j * 2], a2 = s6[j * 2 + 1];
            double mu = (double)a1 / 64.0;
            double varm = (double)a2 / 64.0 - mu * mu;
            double A = (double)ldin(g6, j, f32) / sqrt(4.0 * varm + 1e-5);
            v[i] = (double)acc2[n * 1000 + j] * (-2.0 * A) + (2.0 * A * mu + (double)ldin(b6, j, f32));
            mx = fmax(mx, v[i]);
        } else v[i] = -1e300;
    }
    red[tid] = mx; __syncthreads();
    for (int s = 128; s > 0; s >>= 1) {
        if (tid < s) red[tid] = fmax(red[tid], red[tid + s]);
        __syncthreads();
    }
    mx = red[0]; __syncthreads();
    double sum = 0.0;
#pragma unroll
    for (int i = 0; i < 4; i++) {
        int j = tid + i * 256;
        if (j < 1000) sum += exp(v[i] - mx);
    }
    red[tid] = sum; __syncthreads();
    for (int s = 128; s > 0; s >>= 1) {
        if (tid < s) red[tid] += red[tid + s];
        __syncthreads();
    }
    double ls = log(red[0]);
#pragma unroll
    for (int i = 0; i < 4; i++) {
        int j = tid + i * 256;
        if (j < 1000) {
            float r = (float)(v[i] - mx - ls);
            if (!isfinite(r)) r = -700.0f;
            if (f32) ((float*)outv)[n * 1000 + j] = r;
            else ((bf16*)outv)[n * 1000 + j] = __float2bfloat16(r);
        }
    }
}

extern "C" void kernel_launch(void* const* d_in, const int* in_sizes, int n_in,
                              void* d_out, int out_size, void* d_ws, size_t ws_size,
                              hipStream_t stream) {
    const void* x       = d_in[0];
    const void* bn0_g   = d_in[1];
    const void* bn0_b   = d_in[2];
    const void* conv1_w = d_in[3];
    const void* bn1_g   = d_in[5];
    const void* bn1_b   = d_in[6];
    const void* conv2_w = d_in[7];
    const void* bn2_g   = d_in[9];
    const void* bn2_b   = d_in[10];
    const void* conv3_w = d_in[11];
    const void* bn3_g   = d_in[13];
    const void* bn3_b   = d_in[14];
    const void* conv4_w = d_in[15];
    const void* bn4_g   = d_in[17];
    const void* bn4_b   = d_in[18];
    const void* conv5_w = d_in[19];
    const void* conv5_b = d_in[20];
    const void* fc1_w   = d_in[21];
    const void* bn5_g   = d_in[23];
    const void* bn5_b   = d_in[24];
    const void* fc2_w   = d_in[25];
    const void* bn6_g   = d_in[27];
    const void* bn6_b   = d_in[28];

    char* wsb = (char*)d_ws;
    size_t off = 0;
    auto alloc = [&](size_t bytes) -> void* {
        off = (off + 255) & ~(size_t)255;
        void* p = wsb + off;
        off += bytes;
        return p;
    };

    unsigned* ctl   = (unsigned*)alloc(256);
    unsigned* x2p   = (unsigned*)alloc(2716672);       // 5306*64 uint2
    float*    yq    = (float*)alloc(86933504);         // 64*64*5306 f32
    u16*      m2    = (u16*)alloc(14270464);
    u16*      m3    = (u16*)alloc(4538368);
    u16*      m4    = (u16*)alloc(1294336);
    u16*      acc1  = (u16*)alloc(131072);
    u16*      acc2  = (u16*)alloc(128000);
    float*    ws1f  = (float*)alloc(31488);
    uint2*    w2p   = (uint2*)alloc(20992);
    uint2*    w3p   = (uint2*)alloc(20992);
    uint2*    w4p   = (uint2*)alloc(20992);
    uint2*    w5p   = (uint2*)alloc(10496);
    unsigned* fc1wp = (unsigned*)alloc(106496);
    unsigned* fc2wp = (unsigned*)alloc(128000);
    u64*      stats = (u64*)alloc(14400 * 8);          // s2|s3|s4|s5|s6|..|yb(f64)|fixcnt
    double*   part0 = (double*)alloc(2048);
    unsigned* fixlist = (unsigned*)alloc(FIXCAP * 4);  // 4 MB
    size_t need = (off + 255) & ~(size_t)255;

    u64* s2 = stats;
    u64* s3 = stats + 2048;
    u64* s4 = stats + 4096;
    u64* s5 = stats + 6144;
    u64* s6 = stats + 8192;
    double* yb = (double*)(stats + 12288);             // 2048 f64 bn1 buckets
    unsigned* fixcnt = (unsigned*)(stats + 14340);

    k_probe<<<1, 256, 0, stream>>>(x, ctl);

    if (n_in != 29) {
        k_sentinel<<<250, 256, 0, stream>>>(d_out, ctl, -(3000.0f + (float)n_in));
        return;
    }
    if (ws_size < need) {
        k_sentinel<<<250, 256, 0, stream>>>(d_out, ctl, -1500.0f);
        return;
    }

    k_prep<<<dim3(125, 9), 256, 0, stream>>>(x, conv1_w, conv2_w, conv3_w, conv4_w, conv5_w,
                                             fc1_w, fc2_w, ws1f, w2p, w3p, w4p, w5p,
                                             fc1wp, fc2wp, stats, part0, ctl);

    k_conv1<<<dim3(83, 64), 256, 0, stream>>>(x, part0, bn0_g, bn0_b, ws1f, yq, yb, ctl);
    k_pack_y<<<dim3(21, 64), 256, 0, stream>>>(yq, yb, bn1_g, bn1_b, (uint2*)x2p,
                                               fixcnt, fixlist, ctl);
    k_fix<<<64, 256, 0, stream>>>(fixcnt, fixlist, yb, bn1_g, bn1_b, x, conv1_w,
                                  part0, bn0_g, bn0_b, x2p, ctl);

    k_conv_bin<<<dim3(28, 64, 2), 256, 0, stream>>>((const uint2*)x2p, w2p, m2, 1742, 5306, 64, s2);
    k_conv_binm<<<dim3(9, 64, 2), 256, 0, stream>>>(m2, s2, bn2_g, bn2_b, 64.0 * 1742.0,
                                                    w3p, m3, s3, 554, 1742, 64, ctl);
    k_conv_binm<<<dim3(3, 64, 2), 256, 0, stream>>>(m3, s3, bn3_g, bn3_b, 64.0 * 554.0,
                                                    w4p, m4, s4, 158, 554, 64, ctl);

    k_c5fc1<<<64, 256, 0, stream>>>(m4, s4, bn4_g, bn4_b, w5p, conv5_b, fc1wp, acc1, s5, ctl);
    k_fc2<<<dim3(4, 64), 256, 0, stream>>>(acc1, s5, bn5_g, bn5_b, fc2wp, acc2, s6, ctl);
    k_lsm<<<64, 256, 0, stream>>>(acc2, s6, bn6_g, bn6_b, ctl, d_out);
}